// Round 8
// baseline (626.237 us; speedup 1.0000x reference)
//
#include <hip/hip_runtime.h>

typedef __attribute__((ext_vector_type(8))) short short8v;
typedef __attribute__((ext_vector_type(4))) float f32x4;
typedef __attribute__((ext_vector_type(4))) unsigned int uint4v;

#define GLOBAL_AS(p) ((const __attribute__((address_space(1))) void*)(p))
#define LDS_AS(p)    ((__attribute__((address_space(3))) void*)(p))
#define WAITV(n) asm volatile("s_waitcnt vmcnt(" #n ")" ::: "memory")
#define BARRIER() __builtin_amdgcn_s_barrier()

__device__ __forceinline__ unsigned short f2bf(float f) {
  unsigned int u = __builtin_bit_cast(unsigned int, f);
  u += 0x7fffu + ((u >> 16) & 1u);
  return (unsigned short)(u >> 16);
}
__device__ __forceinline__ float bf2f(unsigned short u) {
  unsigned int x = ((unsigned int)u) << 16;
  return __builtin_bit_cast(float, x);
}

// ---------------------------------------------------------------------------
// Transpose fp32 [K,N] -> bf16 [N,K]
__global__ __launch_bounds__(256) void transpose_to_bf16(
    const float* __restrict__ src, unsigned short* __restrict__ dst,
    int K, int N, int ntx) {
  __shared__ float tile[32][33];
  const int bx = blockIdx.x % ntx;
  const int by = blockIdx.x / ntx;
  const int tx = threadIdx.x & 31, ty = threadIdx.x >> 5;
  const int k0 = by * 32, n0 = bx * 32;
#pragma unroll
  for (int i = 0; i < 32; i += 8)
    tile[ty + i][tx] = src[(size_t)(k0 + ty + i) * N + n0 + tx];
  __syncthreads();
#pragma unroll
  for (int i = 0; i < 32; i += 8)
    dst[(size_t)(n0 + ty + i) * K + k0 + tx] = f2bf(tile[tx][ty + i]);
}

// fp32 -> bf16, 8 elements/thread
__global__ __launch_bounds__(256) void cvt_f32_bf16(
    const float* __restrict__ s, unsigned short* __restrict__ d) {
  size_t i = ((size_t)blockIdx.x * 256 + threadIdx.x) * 8;
  f32x4 v0 = *(const f32x4*)(s + i);
  f32x4 v1 = *(const f32x4*)(s + i + 4);
  union U8 { uint4v v; unsigned short us[8]; } o;
  o.us[0] = f2bf(v0.x); o.us[1] = f2bf(v0.y); o.us[2] = f2bf(v0.z); o.us[3] = f2bf(v0.w);
  o.us[4] = f2bf(v1.x); o.us[5] = f2bf(v1.y); o.us[6] = f2bf(v1.z); o.us[7] = f2bf(v1.w);
  *(uint4v*)(d + i) = o.v;
}

// combined bias concat: b1 = [bd_k|bd_v|bq] (3072), b2 = [bu_k|bu_v] (4096)
__global__ __launch_bounds__(256) void fill_bias(
    const float* __restrict__ bd_k, const float* __restrict__ bd_v,
    const float* __restrict__ bq, const float* __restrict__ bu_k,
    const float* __restrict__ bu_v, float* __restrict__ b1, float* __restrict__ b2) {
  int i = blockIdx.x * 256 + threadIdx.x;
  if (i < 512) b1[i] = bd_k[i];
  else if (i < 1024) b1[i] = bd_v[i - 512];
  else if (i < 3072) b1[i] = bq[i - 1024];
  else if (i < 5120) b2[i - 3072] = bu_k[i - 3072];
  else if (i < 7168) b2[i - 3072] = bu_v[i - 5120];
}

// ---------------------------------------------------------------------------
// 256x256 bf16 GEMM, BK=32, 8 waves (2Mx4N), per-wave 128x64, 16x16x32 MFMA.
// 4-deep LDS ring (4 x 32KB), stage lead = 3 tiles (~1000+cy > HBM latency).
// Register double-buffer: while MFMA consumes frag set for tile T, the 12
// ds_read_b128 for tile T+1 fill the other set; compiler emits counted
// lgkmcnt automatically (no manual LGKM0 drains, no SCHED0).
// Per tile: 1 x { vmcnt(4) ; barrier ; stage(T+3) ; reads(T+1) ; 32 MFMA }.
// vmcnt induction: steady outstanding = {S(T+2), S(T+3)} = 8 at tile top;
// WAITV(4) drains S(T+1) (needed by this slot's reads). Slot reuse safety:
// stage(T+3) -> buf[(T-1)&3]; all waves' reads of buf[T-1] complete before
// mfma(T-1) (compiler lgkm) which precedes barrier(T).  NT must be even, >=4.
template <int OUT_BF16>
__global__ __launch_bounds__(512, 2) void gemm_bt(
    const unsigned short* __restrict__ A, int lda, int nsplit_col, int acol_off,
    const unsigned short* __restrict__ Bt, int ldb,
    const float* __restrict__ bias, void* __restrict__ Cp, int ldc,
    int K, int ntn) {
  __shared__ unsigned short lds[4][2][256 * 32];  // [ring][A|B][row*32+col]
  const int t = threadIdx.x;
  const int lane = t & 63, wave = t >> 6;

  // bijective XCD swizzle (grids here are multiples of 8)
  const int qx = gridDim.x >> 3;
  const int bid = (blockIdx.x & 7) * qx + (blockIdx.x >> 3);
  const int bm = (bid / ntn) * 256;
  const int bn = (bid % ntn) * 256;
  const unsigned short* Ab = A + (bn >= nsplit_col ? acol_off : 0);

  const int wr = wave >> 2, wc = wave & 3;
  const int g = lane >> 4, r = lane & 15;
  const int swz = r & 3;
  const int cchunk = (g ^ swz) << 3;  // deswizzled 16B chunk (elems), uniform
  const int NT = K >> 5;              // BK=32

  f32x4 acc[8][4];
#pragma unroll
  for (int i = 0; i < 8; ++i)
#pragma unroll
    for (int j = 0; j < 4; ++j) acc[i][j] = (f32x4){0.f, 0.f, 0.f, 0.f};

  // staging: 4 issues/tile, each 128 rows x 32 cols (512 thr x 16B).
  // thread t -> row t>>2, chunk t&3; source chunk inverse-XOR-swizzled.
  const int srow = t >> 2;
  const int jsrc = (t & 3) ^ (srow & 3);
  const unsigned short* aptr = Ab + (size_t)(bm + srow) * lda + (jsrc << 3);
  const unsigned short* bptr = Bt + (size_t)(bn + srow) * ldb + (jsrc << 3);
  const int wbase = wave * 512;  // wave-uniform LDS dest base (elems)

  auto stage = [&](int kt) {
    const int buf = kt & 3;
    const unsigned short* ak = aptr + kt * 32;
    const unsigned short* bk = bptr + kt * 32;
    unsigned short* la = &lds[buf][0][wbase];
    unsigned short* lb = &lds[buf][1][wbase];
#pragma unroll
    for (int u = 0; u < 2; ++u) {
      __builtin_amdgcn_global_load_lds(GLOBAL_AS(ak + (size_t)(u * 128) * lda),
                                       LDS_AS(la + u * 4096), 16, 0, 0);
      __builtin_amdgcn_global_load_lds(GLOBAL_AS(bk + (size_t)(u * 128) * ldb),
                                       LDS_AS(lb + u * 4096), 16, 0, 0);
    }
  };

  auto readFrags = [&](int kt, short8v (&af)[8], short8v (&bf)[4]) {
    const unsigned short* la = lds[kt & 3][0];
    const unsigned short* lb = lds[kt & 3][1];
#pragma unroll
    for (int mi = 0; mi < 8; ++mi)
      af[mi] = *(const short8v*)&la[(wr * 128 + mi * 16 + r) * 32 + cchunk];
#pragma unroll
    for (int ni = 0; ni < 4; ++ni)
      bf[ni] = *(const short8v*)&lb[(wc * 64 + ni * 16 + r) * 32 + cchunk];
  };

  auto mfma32 = [&](short8v (&af)[8], short8v (&bf)[4]) {
    __builtin_amdgcn_s_setprio(1);
#pragma unroll
    for (int mi = 0; mi < 8; ++mi)
#pragma unroll
      for (int ni = 0; ni < 4; ++ni)
        acc[mi][ni] = __builtin_amdgcn_mfma_f32_16x16x32_bf16(
            af[mi], bf[ni], acc[mi][ni], 0, 0, 0);
    __builtin_amdgcn_s_setprio(0);
  };

  // prologue: 3 tiles staged (12 issues); drain tile0; pre-read tile0 frags
  stage(0); stage(1); stage(2);
  WAITV(8);
  BARRIER();
  short8v afA[8], bfA[4], afB[8], bfB[4];
  readFrags(0, afA, bfA);

  for (int T = 0; T < NT; T += 2) {
    // ---- tile T: compute set A, read T+1 into set B
    if (T + 2 < NT) { WAITV(4); } else { WAITV(0); }
    BARRIER();
    if (T + 3 < NT) stage(T + 3);
    readFrags(T + 1, afB, bfB);   // T+1 <= NT-1 (NT even)
    mfma32(afA, bfA);
    // ---- tile T+1: compute set B, read T+2 into set A
    if (T + 3 < NT) { WAITV(4); } else { WAITV(0); }
    BARRIER();
    if (T + 4 < NT) stage(T + 4);
    if (T + 2 < NT) readFrags(T + 2, afA, bfA);
    mfma32(afB, bfB);
  }

#pragma unroll
  for (int ni = 0; ni < 4; ++ni) {
    const int col = bn + wc * 64 + ni * 16 + r;
    const float bv = bias[col];
#pragma unroll
    for (int mi = 0; mi < 8; ++mi) {
      const int row0 = bm + wr * 128 + mi * 16 + (g << 2);
#pragma unroll
      for (int j = 0; j < 4; ++j) {
        float v = acc[mi][ni][j] + bv;
        if (OUT_BF16)
          ((unsigned short*)Cp)[(size_t)(row0 + j) * ldc + col] = f2bf(v);
        else
          ((float*)Cp)[(size_t)(row0 + j) * ldc + col] = v;
      }
    }
  }
}

// ---------------------------------------------------------------------------
// Per-token head-vs-head attention (16x16 per token), fp32 math.
__global__ __launch_bounds__(256) void attn_kernel(
    const unsigned short* __restrict__ out1, const unsigned short* __restrict__ kv,
    unsigned short* __restrict__ aout) {
  const int s = blockIdx.x;
  const int t = threadIdx.x;
  __shared__ float qs[16 * 132], ks2[16 * 132], vs[16 * 132];
  __shared__ float attn[256];
  const int h = t >> 4, d0 = (t & 15) * 8;

  union U8 { uint4v v; unsigned short us[8]; };
  U8 qv, kv8, vv;
  qv.v = *(const uint4v*)(out1 + (size_t)s * 3072 + 1024 + t * 8);
  kv8.v = *(const uint4v*)(kv + (size_t)s * 4096 + t * 8);
  vv.v = *(const uint4v*)(kv + (size_t)s * 4096 + 2048 + t * 8);
#pragma unroll
  for (int j = 0; j < 8; ++j) {
    qs[h * 132 + d0 + j] = bf2f(qv.us[j]);
    ks2[h * 132 + d0 + j] = bf2f(kv8.us[j]);
    vs[h * 132 + d0 + j] = bf2f(vv.us[j]);
  }
  __syncthreads();

  const int gg0 = t & 15;
  const f32x4* qrow = (const f32x4*)&qs[h * 132];
  const f32x4* krow = (const f32x4*)&ks2[gg0 * 132];
  float acc = 0.f;
#pragma unroll
  for (int dd = 0; dd < 32; ++dd) {
    f32x4 a4 = qrow[dd], b4 = krow[dd];
    acc += a4.x * b4.x + a4.y * b4.y + a4.z * b4.z + a4.w * b4.w;
  }
  acc *= 0.08838834764831845f;
  float mx = acc;
#pragma unroll
  for (int o = 8; o; o >>= 1) mx = fmaxf(mx, __shfl_xor(mx, o));
  float e = __expf(acc - mx);
  float sm = e;
#pragma unroll
  for (int o = 8; o; o >>= 1) sm += __shfl_xor(sm, o);
  attn[t] = e / sm;
  __syncthreads();

  f32x4 o0 = (f32x4){0.f, 0.f, 0.f, 0.f}, o1 = (f32x4){0.f, 0.f, 0.f, 0.f};
#pragma unroll
  for (int gg = 0; gg < 16; ++gg) {
    const float a = attn[(h << 4) + gg];
    f32x4 v0 = *(const f32x4*)&vs[gg * 132 + d0];
    f32x4 v1 = *(const f32x4*)&vs[gg * 132 + d0 + 4];
    o0 += v0 * a;
    o1 += v1 * a;
  }
  U8 ov;
  ov.us[0] = f2bf(o0.x); ov.us[1] = f2bf(o0.y); ov.us[2] = f2bf(o0.z); ov.us[3] = f2bf(o0.w);
  ov.us[4] = f2bf(o1.x); ov.us[5] = f2bf(o1.y); ov.us[6] = f2bf(o1.z); ov.us[7] = f2bf(o1.w);
  *(uint4v*)(aout + (size_t)s * 2048 + t * 8) = ov.v;
}

// ---------------------------------------------------------------------------
extern "C" void kernel_launch(void* const* d_in, const int* in_sizes, int n_in,
                              void* d_out, int out_size, void* d_ws, size_t ws_size,
                              hipStream_t stream) {
  (void)in_sizes; (void)n_in; (void)out_size; (void)ws_size;
  const float* x    = (const float*)d_in[0];
  const float* Wd_k = (const float*)d_in[1];
  const float* bd_k = (const float*)d_in[2];
  const float* Wu_k = (const float*)d_in[3];
  const float* bu_k = (const float*)d_in[4];
  const float* Wd_v = (const float*)d_in[5];
  const float* bd_v = (const float*)d_in[6];
  const float* Wu_v = (const float*)d_in[7];
  const float* bu_v = (const float*)d_in[8];
  const float* Wq   = (const float*)d_in[9];
  const float* bq   = (const float*)d_in[10];
  const float* Wo   = (const float*)d_in[11];
  const float* bo   = (const float*)d_in[12];

  char* ws = (char*)d_ws;
  unsigned short* w1t  = (unsigned short*)(ws);             // [3072][2048] bf16
  unsigned short* w2t  = (unsigned short*)(ws + 12582912);  // [4096][512]  bf16
  unsigned short* w3t  = (unsigned short*)(ws + 16777216);  // [2048][2048] bf16
  float*          b1   = (float*)(ws + 25165824);           // [3072]
  float*          b2   = (float*)(ws + 25178112);           // [4096]
  unsigned short* xb   = (unsigned short*)(ws + 25194496);  // [16384][2048] bf16
  unsigned short* out1 = (unsigned short*)(ws + 92303360);  // [16384][3072] bf16
  unsigned short* kvb  = (unsigned short*)(ws + 192966656); // [16384][4096] bf16
  unsigned short* attO = xb;  // reuse xb after GEMM1

  dim3 blk(256);

  transpose_to_bf16<<<dim3(16 * 64), blk, 0, stream>>>(Wd_k, w1t,               2048, 512, 16);
  transpose_to_bf16<<<dim3(16 * 64), blk, 0, stream>>>(Wd_v, w1t + 512 * 2048,  2048, 512, 16);
  transpose_to_bf16<<<dim3(64 * 64), blk, 0, stream>>>(Wq,   w1t + 1024 * 2048, 2048, 2048, 64);
  transpose_to_bf16<<<dim3(64 * 16), blk, 0, stream>>>(Wu_k, w2t,               512, 2048, 64);
  transpose_to_bf16<<<dim3(64 * 16), blk, 0, stream>>>(Wu_v, w2t + 2048 * 512,  512, 2048, 64);
  transpose_to_bf16<<<dim3(64 * 64), blk, 0, stream>>>(Wo,   w3t,               2048, 2048, 64);

  fill_bias<<<dim3(28), blk, 0, stream>>>(bd_k, bd_v, bq, bu_k, bu_v, b1, b2);

  cvt_f32_bf16<<<dim3(16384), blk, 0, stream>>>(x, xb);

  // GEMM1: [16384,2048]@[2048,3072] -> out1 (cache_k|cache_v|q)
  gemm_bt<1><<<dim3(64 * 12), dim3(512), 0, stream>>>(
      xb, 2048, 1 << 30, 0, w1t, 2048, b1, out1, 3072, 2048, 12);

  // GEMM2 fused: k|v = [cache_k|cache_v]@blockdiag(Wu_k,Wu_v) -> kvb
  gemm_bt<1><<<dim3(64 * 16), dim3(512), 0, stream>>>(
      out1, 3072, 2048, 512, w2t, 512, b2, kvb, 4096, 512, 16);

  // per-token attention
  attn_kernel<<<dim3(16384), blk, 0, stream>>>(out1, kvb, attO);

  // GEMM3: attO@Wo + bo -> d_out fp32
  gemm_bt<0><<<dim3(64 * 8), dim3(512), 0, stream>>>(
      attO, 2048, 1 << 30, 0, w3t, 2048, bo, (float*)d_out, 2048, 2048, 8);
}